// Round 12
// baseline (4050.835 us; speedup 1.0000x reference)
//
#include <hip/hip_runtime.h>
#include <hip/hip_bf16.h>
#include <math.h>

// Buggy flash-attn fwd (no acc rescale, running-l division) per 64-wide KV
// block, fp32 in/out, bf16 MFMA compute. Reference semantics: l is updated
// once per 64-kv block and BOTH halves' p are divided by that l.
// Round 12: round 11 with the staging-coverage bug fixed -- 256 threads must
// write 16 K elems each (units u_k and u_k+8), not 8; round 11 left K cols
// 64..127 uninitialized -> NaN. All other structure unchanged: 4-wave WGs
// (QB=128), 3 WGs/CU (launch_bounds(256,3)), BN=32 subtiles, deferred
// even-subtile PV (l updates per 64-kv block), V triple-buffered,
// XOR-swizzled K[32][128] / Vt[128][32].

typedef __attribute__((ext_vector_type(8)))  unsigned short ushort8;
typedef __attribute__((ext_vector_type(8)))  __bf16        bf16x8;
typedef __attribute__((ext_vector_type(16))) float         f32x16;
typedef __attribute__((ext_vector_type(4)))  float         floatv4;
typedef __attribute__((ext_vector_type(2)))  unsigned int  uint2v;
typedef __attribute__((ext_vector_type(4)))  unsigned int  uint4v;

#define SQ   4096
#define SKV  4096
#define DH   128
#define BN   32            // MFMA/staging subtile; l-update period = 64 kv
#define QB   128
#define NT   (SKV / BN)    // 128 subtiles
#define KROW 128
#define VROW 32
#define KBUF (32 * KROW)   // 8KB
#define VBUF (DH * VROW)   // 8KB

static __device__ __forceinline__ unsigned pk2(float lo, float hi) {
    unsigned r;
    asm("v_cvt_pk_bf16_f32 %0, %1, %2" : "=v"(r) : "v"(lo), "v"(hi));
    return r;
}

__global__ __launch_bounds__(256, 3) void fa_fwd_buggy(
    const float* __restrict__ Qg, const float* __restrict__ Kg,
    const float* __restrict__ Vg, float* __restrict__ Og)
{
    // LDS: K 2x8KB + Vt 3x8KB = 40KB -> 3 WGs/CU = 120KB.
    __shared__ unsigned short K_lds[2 * KBUF];
    __shared__ unsigned short Vt_lds[3 * VBUF];

    const int tid  = threadIdx.x;
    const int w    = tid >> 6;      // wave 0..3, owns q rows w*32..+31
    const int lane = tid & 63;
    const int c32  = lane & 31;
    const int h    = lane >> 5;
    const int msk8 = 8 * (c32 & 7);

    const int wgid  = blockIdx.x;            // 0..1023
    const int bh    = (wgid & 7) * 4 + (wgid >> 8);
    const int qtile = (wgid >> 3) & 31;
    const int qbase = qtile * QB;
    const float qscale = 0.08838834764831845f * 1.44269504088896341f;

    const float* Qrow = Qg + ((size_t)bh * SQ + qbase + w * 32 + c32) * DH;
    ushort8 qf[8];
    #pragma unroll
    for (int ds = 0; ds < 8; ++ds) {
        floatv4 a = *(const floatv4*)(Qrow + ds * 16 + h * 8);
        floatv4 b = *(const floatv4*)(Qrow + ds * 16 + h * 8 + 4);
        uint4v u;
        u[0] = pk2(a[0]*qscale, a[1]*qscale);
        u[1] = pk2(a[2]*qscale, a[3]*qscale);
        u[2] = pk2(b[0]*qscale, b[1]*qscale);
        u[3] = pk2(b[2]*qscale, b[3]*qscale);
        qf[ds] = __builtin_bit_cast(ushort8, u);
    }

    f32x16 acc[4];
    #pragma unroll
    for (int i = 0; i < 4; ++i)
        #pragma unroll
        for (int r = 0; r < 16; ++r) acc[i][r] = 0.f;

    float l_run = 0.f;
    float ps_prev = 0.f;
    unsigned wprev[8];          // even subtile's unscaled packed p
    #pragma unroll
    for (int i = 0; i < 8; ++i) wprev[i] = 0u;

    const float* Kbh = Kg + (size_t)bh * SKV * DH;
    const float* Vbh = Vg + (size_t)bh * SKV * DH;

    const int n_k = tid >> 3;          // K row 0..31
    const int u_k = tid & 7;           // K 8-elem units {u_k, u_k+8}
    const int a_k = n_k & 7;           // K write XOR (low-3-bit units)
    const int nq  = tid & 7;           // V kv-chunk (kv = 4*nq..+3)
    const int dq  = tid >> 3;          // V d-block (d = 4*dq..+3)

    floatv4 ka0, ka1, kb0, kb1;        // K stage regs (16 elems: units u_k, u_k+8)
    floatv4 va0, va1, va2, va3;        // V stage regs

#define LOAD_TILE(N0) do {                                                   \
        const float* ks_ = Kbh + (size_t)((N0) + n_k) * DH + u_k * 8;        \
        ka0 = *(const floatv4*)(ks_);        ka1 = *(const floatv4*)(ks_+4); \
        kb0 = *(const floatv4*)(ks_ + 64);   kb1 = *(const floatv4*)(ks_+68);\
        const float* vs_ = Vbh + (size_t)((N0) + nq * 4) * DH + dq * 4;      \
        va0 = *(const floatv4*)(vs_);        va1 = *(const floatv4*)(vs_+DH);\
        va2 = *(const floatv4*)(vs_+2*DH);   va3 = *(const floatv4*)(vs_+3*DH);\
    } while (0)

// K: unit j of row n stored at unit j ^ (n&7) (bit 3 untouched: (u_k+8)^a_k
// = (u_k^a_k)+8 -> the +64 store). V: kv-chunk nq of row d stored at chunk
// nq ^ (2*(d&3)) (even mask keeps 16B-read chunk pairs adjacent).
#define STORE_TILE(KS, VS) do {                                              \
        unsigned short* kd_ = &K_lds[(KS) * KBUF];                           \
        unsigned short* vd_ = &Vt_lds[(VS) * VBUF];                          \
        uint4v u_;                                                           \
        u_[0]=pk2(ka0[0],ka0[1]); u_[1]=pk2(ka0[2],ka0[3]);                  \
        u_[2]=pk2(ka1[0],ka1[1]); u_[3]=pk2(ka1[2],ka1[3]);                  \
        *(uint4v*)&kd_[n_k * KROW + 8 * (u_k ^ a_k)] = u_;                   \
        u_[0]=pk2(kb0[0],kb0[1]); u_[1]=pk2(kb0[2],kb0[3]);                  \
        u_[2]=pk2(kb1[0],kb1[1]); u_[3]=pk2(kb1[2],kb1[3]);                  \
        *(uint4v*)&kd_[n_k * KROW + 8 * (u_k ^ a_k) + 64] = u_;              \
        _Pragma("unroll")                                                    \
        for (int i_ = 0; i_ < 4; ++i_) {                                     \
            const int d_ = dq * 4 + i_;                                      \
            uint2v p_;                                                       \
            p_[0] = pk2(va0[i_], va1[i_]);                                   \
            p_[1] = pk2(va2[i_], va3[i_]);                                   \
            *(uint2v*)&vd_[d_ * VROW + 4 * (nq ^ (2 * (d_ & 3)))] = p_;      \
        }                                                                    \
    } while (0)

#define PV_HALF(WSC, VS) do {                                                \
        const unsigned short* vb_ = &Vt_lds[(VS) * VBUF];                    \
        ushort8 pa_[2];                                                      \
        _Pragma("unroll")                                                    \
        for (int st_ = 0; st_ < 2; ++st_) {                                  \
            const int b_ = 4 * st_;                                          \
            auto rA_ = __builtin_amdgcn_permlane32_swap(                     \
                          (int)WSC[b_ + 0], (int)WSC[b_ + 2], false, false); \
            auto rB_ = __builtin_amdgcn_permlane32_swap(                     \
                          (int)WSC[b_ + 1], (int)WSC[b_ + 3], false, false); \
            uint4v pw_;                                                      \
            pw_[0] = (unsigned)rA_[0];                                       \
            pw_[1] = (unsigned)rB_[0];                                       \
            pw_[2] = (unsigned)rA_[1];                                       \
            pw_[3] = (unsigned)rB_[1];                                       \
            pa_[st_] = __builtin_bit_cast(ushort8, pw_);                     \
        }                                                                    \
        __builtin_amdgcn_s_setprio(1);                                       \
        _Pragma("unroll")                                                    \
        for (int dt_ = 0; dt_ < 4; ++dt_) {                                  \
            const int d_ = dt_ * 32 + c32;                                   \
            _Pragma("unroll")                                                \
            for (int st_ = 0; st_ < 2; ++st_) {                              \
                ushort8 vv_ = *(const ushort8*)&vb_[d_ * VROW                \
                                 + 8 * ((2 * st_ + h) ^ (d_ & 3))];          \
                acc[dt_] = __builtin_amdgcn_mfma_f32_32x32x16_bf16(          \
                    __builtin_bit_cast(bf16x8, pa_[st_]),                    \
                    __builtin_bit_cast(bf16x8, vv_), acc[dt_], 0, 0, 0);     \
            }                                                                \
        }                                                                    \
        __builtin_amdgcn_s_setprio(0);                                       \
    } while (0)

    // prologue: subtile 0 -> K0/V0, subtile 1 -> regs
    LOAD_TILE(0);
    STORE_TILE(0, 0);
    LOAD_TILE(BN);
    __syncthreads();

    int vs = 0;  // V slot of subtile t
    for (int t = 0; t < NT; ++t) {
        const int vs1 = (vs == 2) ? 0 : vs + 1;     // slot of t+1
        if (t + 1 < NT) {
            STORE_TILE((t + 1) & 1, vs1);
            if (t + 2 < NT) LOAD_TILE((size_t)(t + 2) * BN);
        }
        const unsigned short* Kb = &K_lds[(t & 1) * KBUF];

        // ---- S = K Q^T (swapped, 32x32x16): C col = c32 = q,
        // row kv = (r&3)+8*(r>>2)+4*h ----
        f32x16 s;
        #pragma unroll
        for (int r = 0; r < 16; ++r) s[r] = 0.f;
        __builtin_amdgcn_s_setprio(1);
        #pragma unroll
        for (int ds = 0; ds < 8; ++ds) {
            ushort8 kf = *(const ushort8*)&Kb[c32 * KROW + ((ds * 16 + h * 8) ^ msk8)];
            s = __builtin_amdgcn_mfma_f32_32x32x16_bf16(
                    __builtin_bit_cast(bf16x8, kf),
                    __builtin_bit_cast(bf16x8, qf[ds]), s, 0, 0, 0);
        }
        __builtin_amdgcn_s_setprio(0);

        // ---- exp2 (m-hat = 0) + subtile sum ----
        #pragma unroll
        for (int r = 0; r < 16; ++r)
            s[r] = __builtin_amdgcn_exp2f(s[r]);
        float q0 = (s[0]  + s[1])  + (s[2]  + s[3]);
        float q1 = (s[4]  + s[5])  + (s[6]  + s[7]);
        float q2 = (s[8]  + s[9])  + (s[10] + s[11]);
        float q3 = (s[12] + s[13]) + (s[14] + s[15]);
        float ps = (q0 + q1) + (q2 + q3);
        ps += __shfl_xor(ps, 32);

        if ((t & 1) == 0) {
            // even half: stash unscaled packed p; PV deferred to odd iter
            ps_prev = ps;
            #pragma unroll
            for (int i = 0; i < 8; ++i)
                wprev[i] = pk2(s[2*i], s[2*i+1]);
        } else {
            // odd half: one l update per 64-kv block (reference semantics)
            const float ln = l_run + ps_prev + ps;
            l_run = ln;
            const float inv = __builtin_amdgcn_rcpf(ln);

            unsigned w0[8], w1[8];
            #pragma unroll
            for (int i = 0; i < 8; ++i) {
                float lo0 = __builtin_bit_cast(float, wprev[i] << 16);
                float hi0 = __builtin_bit_cast(float, wprev[i] & 0xffff0000u);
                w0[i] = pk2(lo0 * inv, hi0 * inv);
                w1[i] = pk2(s[2*i] * inv, s[2*i+1] * inv);
            }
            const int vs_prev = (vs == 0) ? 2 : vs - 1;  // slot of t-1
            PV_HALF(w0, vs_prev);
            PV_HALF(w1, vs);
        }

        __syncthreads();   // subtile t reads done; K[(t+1)&1], V[vs1] ready
        vs = vs1;
    }

    // ---- epilogue: PV C layout: col = c32 = d-local,
    // row q_local = (r&3) + 8*(r>>2) + 4*h ----
    float* ob = Og + ((size_t)bh * SQ + qbase + w * 32) * DH + c32;
    #pragma unroll
    for (int dt = 0; dt < 4; ++dt) {
        #pragma unroll
        for (int r = 0; r < 16; ++r) {
            const int qrow = (r & 3) + 8 * (r >> 2) + 4 * h;
            ob[(size_t)qrow * DH + dt * 32] = acc[dt][r];
        }
    }
}

extern "C" void kernel_launch(void* const* d_in, const int* in_sizes, int n_in,
                              void* d_out, int out_size, void* d_ws, size_t ws_size,
                              hipStream_t stream) {
    const float* q = (const float*)d_in[0];
    const float* k = (const float*)d_in[1];
    const float* v = (const float*)d_in[2];
    float* o = (float*)d_out;
    dim3 grid((SQ / QB) * 32);   // 1024 WGs
    fa_fwd_buggy<<<grid, 256, 0, stream>>>(q, k, v, o);
}

// Round 13
// 747.020 us; speedup vs baseline: 5.4227x; 5.4227x over previous
//
#include <hip/hip_runtime.h>
#include <hip/hip_bf16.h>
#include <math.h>

// Buggy flash-attn fwd (no acc rescale, running-l division) per 64-wide KV
// block, fp32 in/out, bf16 MFMA compute. l is updated once per 64-kv block
// and BOTH halves' p are divided by that l (reference semantics).
// Round 13: round 12 with launch_bounds(256,2) instead of (256,3).
// Rounds 10/12 mapped the wall: this algorithm needs ~180 regs/wave ->
// 3 waves/SIMD (168-reg cap) ALWAYS spills; 2 waves/SIMD is the ceiling.
// At (256,2) there is no spill, and the 40KB LDS lets TWO independent WGs
// co-reside per CU (80KB) -> cross-WG overlap of barrier/staging idle,
// which the monolithic 8-wave WG (round 8, 299us) structurally forbids.

typedef __attribute__((ext_vector_type(8)))  unsigned short ushort8;
typedef __attribute__((ext_vector_type(8)))  __bf16        bf16x8;
typedef __attribute__((ext_vector_type(16))) float         f32x16;
typedef __attribute__((ext_vector_type(4)))  float         floatv4;
typedef __attribute__((ext_vector_type(2)))  unsigned int  uint2v;
typedef __attribute__((ext_vector_type(4)))  unsigned int  uint4v;

#define SQ   4096
#define SKV  4096
#define DH   128
#define BN   32            // MFMA/staging subtile; l-update period = 64 kv
#define QB   128
#define NT   (SKV / BN)    // 128 subtiles
#define KROW 128
#define VROW 32
#define KBUF (32 * KROW)   // 8KB
#define VBUF (DH * VROW)   // 8KB

static __device__ __forceinline__ unsigned pk2(float lo, float hi) {
    unsigned r;
    asm("v_cvt_pk_bf16_f32 %0, %1, %2" : "=v"(r) : "v"(lo), "v"(hi));
    return r;
}

__global__ __launch_bounds__(256, 2) void fa_fwd_buggy(
    const float* __restrict__ Qg, const float* __restrict__ Kg,
    const float* __restrict__ Vg, float* __restrict__ Og)
{
    // LDS: K 2x8KB + Vt 3x8KB = 40KB -> 2 WGs/CU = 80KB.
    __shared__ unsigned short K_lds[2 * KBUF];
    __shared__ unsigned short Vt_lds[3 * VBUF];

    const int tid  = threadIdx.x;
    const int w    = tid >> 6;      // wave 0..3, owns q rows w*32..+31
    const int lane = tid & 63;
    const int c32  = lane & 31;
    const int h    = lane >> 5;
    const int msk8 = 8 * (c32 & 7);

    const int wgid  = blockIdx.x;            // 0..1023
    const int bh    = (wgid & 7) * 4 + (wgid >> 8);
    const int qtile = (wgid >> 3) & 31;
    const int qbase = qtile * QB;
    const float qscale = 0.08838834764831845f * 1.44269504088896341f;

    const float* Qrow = Qg + ((size_t)bh * SQ + qbase + w * 32 + c32) * DH;
    ushort8 qf[8];
    #pragma unroll
    for (int ds = 0; ds < 8; ++ds) {
        floatv4 a = *(const floatv4*)(Qrow + ds * 16 + h * 8);
        floatv4 b = *(const floatv4*)(Qrow + ds * 16 + h * 8 + 4);
        uint4v u;
        u[0] = pk2(a[0]*qscale, a[1]*qscale);
        u[1] = pk2(a[2]*qscale, a[3]*qscale);
        u[2] = pk2(b[0]*qscale, b[1]*qscale);
        u[3] = pk2(b[2]*qscale, b[3]*qscale);
        qf[ds] = __builtin_bit_cast(ushort8, u);
    }

    f32x16 acc[4];
    #pragma unroll
    for (int i = 0; i < 4; ++i)
        #pragma unroll
        for (int r = 0; r < 16; ++r) acc[i][r] = 0.f;

    float l_run = 0.f;
    float ps_prev = 0.f;
    unsigned wprev[8];          // even subtile's unscaled packed p
    #pragma unroll
    for (int i = 0; i < 8; ++i) wprev[i] = 0u;

    const float* Kbh = Kg + (size_t)bh * SKV * DH;
    const float* Vbh = Vg + (size_t)bh * SKV * DH;

    const int n_k = tid >> 3;          // K row 0..31
    const int u_k = tid & 7;           // K 8-elem units {u_k, u_k+8}
    const int a_k = n_k & 7;           // K write XOR (low-3-bit units)
    const int nq  = tid & 7;           // V kv-chunk (kv = 4*nq..+3)
    const int dq  = tid >> 3;          // V d-block (d = 4*dq..+3)

    floatv4 ka0, ka1, kb0, kb1;        // K stage regs (units u_k, u_k+8)
    floatv4 va0, va1, va2, va3;        // V stage regs

#define LOAD_TILE(N0) do {                                                   \
        const float* ks_ = Kbh + (size_t)((N0) + n_k) * DH + u_k * 8;        \
        ka0 = *(const floatv4*)(ks_);        ka1 = *(const floatv4*)(ks_+4); \
        kb0 = *(const floatv4*)(ks_ + 64);   kb1 = *(const floatv4*)(ks_+68);\
        const float* vs_ = Vbh + (size_t)((N0) + nq * 4) * DH + dq * 4;      \
        va0 = *(const floatv4*)(vs_);        va1 = *(const floatv4*)(vs_+DH);\
        va2 = *(const floatv4*)(vs_+2*DH);   va3 = *(const floatv4*)(vs_+3*DH);\
    } while (0)

// K: unit j of row n stored at unit j ^ (n&7) (bit 3 untouched). V: kv-chunk
// nq of row d stored at chunk nq ^ (2*(d&3)) (even mask keeps 16B pairs).
#define STORE_TILE(KS, VS) do {                                              \
        unsigned short* kd_ = &K_lds[(KS) * KBUF];                           \
        unsigned short* vd_ = &Vt_lds[(VS) * VBUF];                          \
        uint4v u_;                                                           \
        u_[0]=pk2(ka0[0],ka0[1]); u_[1]=pk2(ka0[2],ka0[3]);                  \
        u_[2]=pk2(ka1[0],ka1[1]); u_[3]=pk2(ka1[2],ka1[3]);                  \
        *(uint4v*)&kd_[n_k * KROW + 8 * (u_k ^ a_k)] = u_;                   \
        u_[0]=pk2(kb0[0],kb0[1]); u_[1]=pk2(kb0[2],kb0[3]);                  \
        u_[2]=pk2(kb1[0],kb1[1]); u_[3]=pk2(kb1[2],kb1[3]);                  \
        *(uint4v*)&kd_[n_k * KROW + 8 * (u_k ^ a_k) + 64] = u_;              \
        _Pragma("unroll")                                                    \
        for (int i_ = 0; i_ < 4; ++i_) {                                     \
            const int d_ = dq * 4 + i_;                                      \
            uint2v p_;                                                       \
            p_[0] = pk2(va0[i_], va1[i_]);                                   \
            p_[1] = pk2(va2[i_], va3[i_]);                                   \
            *(uint2v*)&vd_[d_ * VROW + 4 * (nq ^ (2 * (d_ & 3)))] = p_;      \
        }                                                                    \
    } while (0)

#define PV_HALF(WSC, VS) do {                                                \
        const unsigned short* vb_ = &Vt_lds[(VS) * VBUF];                    \
        ushort8 pa_[2];                                                      \
        _Pragma("unroll")                                                    \
        for (int st_ = 0; st_ < 2; ++st_) {                                  \
            const int b_ = 4 * st_;                                          \
            auto rA_ = __builtin_amdgcn_permlane32_swap(                     \
                          (int)WSC[b_ + 0], (int)WSC[b_ + 2], false, false); \
            auto rB_ = __builtin_amdgcn_permlane32_swap(                     \
                          (int)WSC[b_ + 1], (int)WSC[b_ + 3], false, false); \
            uint4v pw_;                                                      \
            pw_[0] = (unsigned)rA_[0];                                       \
            pw_[1] = (unsigned)rB_[0];                                       \
            pw_[2] = (unsigned)rA_[1];                                       \
            pw_[3] = (unsigned)rB_[1];                                       \
            pa_[st_] = __builtin_bit_cast(ushort8, pw_);                     \
        }                                                                    \
        __builtin_amdgcn_s_setprio(1);                                       \
        _Pragma("unroll")                                                    \
        for (int dt_ = 0; dt_ < 4; ++dt_) {                                  \
            const int d_ = dt_ * 32 + c32;                                   \
            _Pragma("unroll")                                                \
            for (int st_ = 0; st_ < 2; ++st_) {                              \
                ushort8 vv_ = *(const ushort8*)&vb_[d_ * VROW                \
                                 + 8 * ((2 * st_ + h) ^ (d_ & 3))];          \
                acc[dt_] = __builtin_amdgcn_mfma_f32_32x32x16_bf16(          \
                    __builtin_bit_cast(bf16x8, pa_[st_]),                    \
                    __builtin_bit_cast(bf16x8, vv_), acc[dt_], 0, 0, 0);     \
            }                                                                \
        }                                                                    \
        __builtin_amdgcn_s_setprio(0);                                       \
    } while (0)

    // prologue: subtile 0 -> K0/V0, subtile 1 -> regs
    LOAD_TILE(0);
    STORE_TILE(0, 0);
    LOAD_TILE(BN);
    __syncthreads();

    int vs = 0;  // V slot of subtile t
    for (int t = 0; t < NT; ++t) {
        const int vs1 = (vs == 2) ? 0 : vs + 1;     // slot of t+1
        if (t + 1 < NT) {
            STORE_TILE((t + 1) & 1, vs1);
            if (t + 2 < NT) LOAD_TILE((size_t)(t + 2) * BN);
        }
        const unsigned short* Kb = &K_lds[(t & 1) * KBUF];

        // ---- S = K Q^T (swapped, 32x32x16): C col = c32 = q,
        // row kv = (r&3)+8*(r>>2)+4*h ----
        f32x16 s;
        #pragma unroll
        for (int r = 0; r < 16; ++r) s[r] = 0.f;
        __builtin_amdgcn_s_setprio(1);
        #pragma unroll
        for (int ds = 0; ds < 8; ++ds) {
            ushort8 kf = *(const ushort8*)&Kb[c32 * KROW + ((ds * 16 + h * 8) ^ msk8)];
            s = __builtin_amdgcn_mfma_f32_32x32x16_bf16(
                    __builtin_bit_cast(bf16x8, kf),
                    __builtin_bit_cast(bf16x8, qf[ds]), s, 0, 0, 0);
        }
        __builtin_amdgcn_s_setprio(0);

        // ---- exp2 (m-hat = 0) + subtile sum ----
        #pragma unroll
        for (int r = 0; r < 16; ++r)
            s[r] = __builtin_amdgcn_exp2f(s[r]);
        float q0 = (s[0]  + s[1])  + (s[2]  + s[3]);
        float q1 = (s[4]  + s[5])  + (s[6]  + s[7]);
        float q2 = (s[8]  + s[9])  + (s[10] + s[11]);
        float q3 = (s[12] + s[13]) + (s[14] + s[15]);
        float ps = (q0 + q1) + (q2 + q3);
        ps += __shfl_xor(ps, 32);

        if ((t & 1) == 0) {
            // even half: stash unscaled packed p; PV deferred to odd iter
            ps_prev = ps;
            #pragma unroll
            for (int i = 0; i < 8; ++i)
                wprev[i] = pk2(s[2*i], s[2*i+1]);
        } else {
            // odd half: one l update per 64-kv block (reference semantics)
            const float ln = l_run + ps_prev + ps;
            l_run = ln;
            const float inv = __builtin_amdgcn_rcpf(ln);

            unsigned w0[8], w1[8];
            #pragma unroll
            for (int i = 0; i < 8; ++i) {
                float lo0 = __builtin_bit_cast(float, wprev[i] << 16);
                float hi0 = __builtin_bit_cast(float, wprev[i] & 0xffff0000u);
                w0[i] = pk2(lo0 * inv, hi0 * inv);
                w1[i] = pk2(s[2*i] * inv, s[2*i+1] * inv);
            }
            const int vs_prev = (vs == 0) ? 2 : vs - 1;  // slot of t-1
            PV_HALF(w0, vs_prev);
            PV_HALF(w1, vs);
        }

        __syncthreads();   // subtile t reads done; K[(t+1)&1], V[vs1] ready
        vs = vs1;
    }

    // ---- epilogue: PV C layout: col = c32 = d-local,
    // row q_local = (r&3) + 8*(r>>2) + 4*h ----
    float* ob = Og + ((size_t)bh * SQ + qbase + w * 32) * DH + c32;
    #pragma unroll
    for (int dt = 0; dt < 4; ++dt) {
        #pragma unroll
        for (int r = 0; r < 16; ++r) {
            const int qrow = (r & 3) + 8 * (r >> 2) + 4 * h;
            ob[(size_t)qrow * DH + dt * 32] = acc[dt][r];
        }
    }
}

extern "C" void kernel_launch(void* const* d_in, const int* in_sizes, int n_in,
                              void* d_out, int out_size, void* d_ws, size_t ws_size,
                              hipStream_t stream) {
    const float* q = (const float*)d_in[0];
    const float* k = (const float*)d_in[1];
    const float* v = (const float*)d_in[2];
    float* o = (float*)d_out;
    dim3 grid((SQ / QB) * 32);   // 1024 WGs
    fa_fwd_buggy<<<grid, 256, 0, stream>>>(q, k, v, o);
}

// Round 14
// 346.863 us; speedup vs baseline: 11.6785x; 2.1536x over previous
//
#include <hip/hip_runtime.h>
#include <hip/hip_bf16.h>
#include <math.h>

// Buggy flash-attn fwd (no acc rescale, running-l division) per 64-wide KV
// block, fp32 in/out, bf16 MFMA compute.
// Round 14: round 8's exact compute structure (BN=64, padded KLD=136/VTLD=72
// layouts, identical physical LDS image) but as 4-wave WGs (QB=128) so TWO
// independent WGs co-reside per CU (70KB LDS each, 140 <= 160KB; same 8
// waves/CU as round 8 -- the reg ceiling -- but half the barrier sync domain
// + cross-WG pipe overlap). Staging maps re-derived for 256 threads
// (bank-checked: K 8-lane groups = b128 minimum; V 2-way = free). P packed
// to bf16 UNSCALED per-ns (frees s early -> no spill; numerics proven by
// round 12), scaled by 1/l after the l-update, then permlane32_swap -> pa.

typedef __attribute__((ext_vector_type(8)))  unsigned short ushort8;
typedef __attribute__((ext_vector_type(8)))  __bf16        bf16x8;
typedef __attribute__((ext_vector_type(16))) float         f32x16;
typedef __attribute__((ext_vector_type(4)))  float         floatv4;
typedef __attribute__((ext_vector_type(2)))  unsigned int  uint2v;
typedef __attribute__((ext_vector_type(4)))  unsigned int  uint4v;

#define SQ   4096
#define SKV  4096
#define DH   128
#define BN   64
#define QB   128
#define NT   (SKV / BN)   // 64
#define KLD  136   // K LDS row stride (bf16 elems): 128 + 8 pad (round-8 layout)
#define VTLD 72    // Vt row stride: 64 data + 8 pad, 8-unit XOR swizzled
#define KBUF (64 * KLD)
#define VBUF (DH * VTLD)

static __device__ __forceinline__ unsigned pk2(float lo, float hi) {
    unsigned r;
    asm("v_cvt_pk_bf16_f32 %0, %1, %2" : "=v"(r) : "v"(lo), "v"(hi));
    return r;
}

__global__ __launch_bounds__(256, 2) void fa_fwd_buggy(
    const float* __restrict__ Qg, const float* __restrict__ Kg,
    const float* __restrict__ Vg, float* __restrict__ Og)
{
    // LDS: 2 x (K 17.4KB + Vt 18.4KB) = 70KB -> 2 WGs/CU (140KB of 160KB).
    __shared__ unsigned short K_lds[2 * KBUF];
    __shared__ unsigned short Vt_lds[2 * VBUF];

    const int tid  = threadIdx.x;
    const int w    = tid >> 6;      // wave 0..3, owns q rows w*32..+31
    const int lane = tid & 63;
    const int c32  = lane & 31;
    const int h    = lane >> 5;

    // bh->XCD grouping: 4 bh per XCD, 32 qtiles each (1024 WGs).
    const int wgid  = blockIdx.x;
    const int bh    = (wgid & 7) * 4 + (wgid >> 8);
    const int qtile = (wgid >> 3) & 31;
    const int qbase = qtile * QB;
    const float qscale = 0.08838834764831845f * 1.44269504088896341f;

    // ---- Q fragments (B-operand of swapped QK): col n = c32 = q-row,
    // k = ds*16 + h*8 + j ----
    const float* Qrow = Qg + ((size_t)bh * SQ + qbase + w * 32 + c32) * DH;
    ushort8 qf[8];
    #pragma unroll
    for (int ds = 0; ds < 8; ++ds) {
        floatv4 a = *(const floatv4*)(Qrow + ds * 16 + h * 8);
        floatv4 b = *(const floatv4*)(Qrow + ds * 16 + h * 8 + 4);
        uint4v u;
        u[0] = pk2(a[0]*qscale, a[1]*qscale);
        u[1] = pk2(a[2]*qscale, a[3]*qscale);
        u[2] = pk2(b[0]*qscale, b[1]*qscale);
        u[3] = pk2(b[2]*qscale, b[3]*qscale);
        qf[ds] = __builtin_bit_cast(ushort8, u);
    }

    f32x16 acc[4];
    #pragma unroll
    for (int i = 0; i < 4; ++i)
        #pragma unroll
        for (int r = 0; r < 16; ++r) acc[i][r] = 0.f;

    float l_run = 0.f;   // running denominator, m-hat = 0 domain

    const float* Kbh = Kg + (size_t)bh * SKV * DH;
    const float* Vbh = Vg + (size_t)bh * SKV * DH;

    // staging maps (256 threads, 32 elems each for K and V)
    const int n_k = tid >> 2;          // K row 0..63
    const int u_k = tid & 3;           // K units {u_k, u_k+4, u_k+8, u_k+12}
    const int nq  = tid >> 5;          // V kv-oct (kv = 8*nq..+7), 0..7
    const int dq  = tid & 31;          // V d-block (d = 4*dq..+3)
    const int vswz = (dq >> 1) & 7;    // = (d>>3)&7 for all 4 d in block

    floatv4 ka0, ka1, kb0, kb1, kc0, kc1, ke0, ke1;   // K stage (32 elems)
    floatv4 va0, va1, va2, va3, va4, va5, va6, va7;   // V stage (32 elems)

#define LOAD_TILE(N0) do {                                                   \
        const float* ks_ = Kbh + (size_t)((N0) + n_k) * DH + u_k * 8;        \
        ka0 = *(const floatv4*)(ks_);      ka1 = *(const floatv4*)(ks_+4);   \
        kb0 = *(const floatv4*)(ks_+32);   kb1 = *(const floatv4*)(ks_+36);  \
        kc0 = *(const floatv4*)(ks_+64);   kc1 = *(const floatv4*)(ks_+68);  \
        ke0 = *(const floatv4*)(ks_+96);   ke1 = *(const floatv4*)(ks_+100); \
        const float* vs_ = Vbh + (size_t)((N0) + nq * 8) * DH + dq * 4;      \
        va0 = *(const floatv4*)(vs_);        va1 = *(const floatv4*)(vs_+DH);\
        va2 = *(const floatv4*)(vs_+2*DH);   va3 = *(const floatv4*)(vs_+3*DH);\
        va4 = *(const floatv4*)(vs_+4*DH);   va5 = *(const floatv4*)(vs_+5*DH);\
        va6 = *(const floatv4*)(vs_+6*DH);   va7 = *(const floatv4*)(vs_+7*DH);\
    } while (0)

// Physical LDS image identical to round 8: K row n, 8-elem unit j at
// kd[n*KLD + j*8]; V chunk c (kv 4c..4c+3) of row d at
// vd[d*VTLD + ((c>>1)^vswz)*8 + (c&1)*4]. Here c = 2*nq + m.
#define STORE_TILE(B) do {                                                   \
        unsigned short* kd_ = &K_lds[(B) * KBUF];                            \
        unsigned short* vd_ = &Vt_lds[(B) * VBUF];                           \
        uint4v u_;                                                           \
        u_[0]=pk2(ka0[0],ka0[1]); u_[1]=pk2(ka0[2],ka0[3]);                  \
        u_[2]=pk2(ka1[0],ka1[1]); u_[3]=pk2(ka1[2],ka1[3]);                  \
        *(uint4v*)&kd_[n_k * KLD + u_k * 8] = u_;                            \
        u_[0]=pk2(kb0[0],kb0[1]); u_[1]=pk2(kb0[2],kb0[3]);                  \
        u_[2]=pk2(kb1[0],kb1[1]); u_[3]=pk2(kb1[2],kb1[3]);                  \
        *(uint4v*)&kd_[n_k * KLD + (u_k + 4) * 8] = u_;                      \
        u_[0]=pk2(kc0[0],kc0[1]); u_[1]=pk2(kc0[2],kc0[3]);                  \
        u_[2]=pk2(kc1[0],kc1[1]); u_[3]=pk2(kc1[2],kc1[3]);                  \
        *(uint4v*)&kd_[n_k * KLD + (u_k + 8) * 8] = u_;                      \
        u_[0]=pk2(ke0[0],ke0[1]); u_[1]=pk2(ke0[2],ke0[3]);                  \
        u_[2]=pk2(ke1[0],ke1[1]); u_[3]=pk2(ke1[2],ke1[3]);                  \
        *(uint4v*)&kd_[n_k * KLD + (u_k + 12) * 8] = u_;                     \
        _Pragma("unroll")                                                    \
        for (int i_ = 0; i_ < 4; ++i_) {                                     \
            const int d_ = dq * 4 + i_;                                      \
            uint2v p_;                                                       \
            p_[0] = pk2(va0[i_], va1[i_]);                                   \
            p_[1] = pk2(va2[i_], va3[i_]);                                   \
            *(uint2v*)&vd_[d_ * VTLD + (nq ^ vswz) * 8] = p_;                \
            p_[0] = pk2(va4[i_], va5[i_]);                                   \
            p_[1] = pk2(va6[i_], va7[i_]);                                   \
            *(uint2v*)&vd_[d_ * VTLD + (nq ^ vswz) * 8 + 4] = p_;            \
        }                                                                    \
    } while (0)

    // prologue: tile 0 -> buf0, tile 1 -> regs
    LOAD_TILE(0);
    STORE_TILE(0);
    LOAD_TILE(BN);
    __syncthreads();

    for (int t = 0; t < NT; ++t) {
        if (t + 1 < NT) {
            STORE_TILE((t + 1) & 1);
            if (t + 2 < NT) LOAD_TILE((size_t)(t + 2) * BN);
        }
        const unsigned short* Kb = &K_lds[(t & 1) * KBUF];
        const unsigned short* Vb = &Vt_lds[(t & 1) * VBUF];

        // ---- per ns: QK (8 MFMA) -> exp2 -> sum -> pack UNSCALED bf16.
        // s freed immediately (reg pressure); ns=1 MFMAs overlap ns=0 VALU. ----
        unsigned wrdU[2][8];
        float psn[2];
        #pragma unroll
        for (int ns = 0; ns < 2; ++ns) {
            f32x16 s;
            #pragma unroll
            for (int r = 0; r < 16; ++r) s[r] = 0.f;
            __builtin_amdgcn_s_setprio(1);
            #pragma unroll
            for (int ds = 0; ds < 8; ++ds) {
                ushort8 kf = *(const ushort8*)&Kb[(ns * 32 + c32) * KLD + ds * 16 + h * 8];
                s = __builtin_amdgcn_mfma_f32_32x32x16_bf16(
                        __builtin_bit_cast(bf16x8, kf),
                        __builtin_bit_cast(bf16x8, qf[ds]), s, 0, 0, 0);
            }
            __builtin_amdgcn_s_setprio(0);
            #pragma unroll
            for (int r = 0; r < 16; ++r)
                s[r] = __builtin_amdgcn_exp2f(s[r]);
            float q0 = (s[0]  + s[1])  + (s[2]  + s[3]);
            float q1 = (s[4]  + s[5])  + (s[6]  + s[7]);
            float q2 = (s[8]  + s[9])  + (s[10] + s[11]);
            float q3 = (s[12] + s[13]) + (s[14] + s[15]);
            psn[ns] = (q0 + q1) + (q2 + q3);
            #pragma unroll
            for (int i = 0; i < 8; ++i)
                wrdU[ns][i] = pk2(s[2*i], s[2*i+1]);
        }

        // ---- one l update per 64-kv block (reference semantics) ----
        float ps = psn[0] + psn[1];
        ps += __shfl_xor(ps, 32);          // combine the two k-halves
        const float ln = l_run + ps;
        l_run = ln;
        const float inv = __builtin_amdgcn_rcpf(ln);

        // ---- scale packed p by 1/l (unpack-mul-repack; round-12-proven),
        // then redistribute to PV A-frags via two-input permlane32_swap ----
        ushort8 pa[4];
        #pragma unroll
        for (int step = 0; step < 4; ++step) {
            const int ns   = step >> 1;
            const int base = 4 * (step & 1);
            unsigned ws[4];
            #pragma unroll
            for (int k = 0; k < 4; ++k) {
                const unsigned uw = wrdU[ns][base + k];
                float lo = __builtin_bit_cast(float, uw << 16);
                float hi = __builtin_bit_cast(float, uw & 0xffff0000u);
                ws[k] = pk2(lo * inv, hi * inv);
            }
            auto rA = __builtin_amdgcn_permlane32_swap((int)ws[0], (int)ws[2], false, false);
            auto rB = __builtin_amdgcn_permlane32_swap((int)ws[1], (int)ws[3], false, false);
            uint4v pw;
            pw[0] = (unsigned)rA[0];   // j0,1 : kv 16*step + 8h + {0,1}
            pw[1] = (unsigned)rB[0];   // j2,3
            pw[2] = (unsigned)rA[1];   // j4,5
            pw[3] = (unsigned)rB[1];   // j6,7
            pa[step] = __builtin_bit_cast(ushort8, pw);
        }

        // ---- PV (32x32x16): B col = c32 = d-local, k = 16*step + 8h + j ----
        __builtin_amdgcn_s_setprio(1);
        #pragma unroll
        for (int dt = 0; dt < 4; ++dt) {
            const int d  = dt * 32 + c32;
            const int fz = (d >> 3) & 7;
            #pragma unroll
            for (int step = 0; step < 4; ++step) {
                ushort8 vb = *(const ushort8*)&Vb[d * VTLD + (((2*step + h) ^ fz) * 8)];
                acc[dt] = __builtin_amdgcn_mfma_f32_32x32x16_bf16(
                    __builtin_bit_cast(bf16x8, pa[step]),
                    __builtin_bit_cast(bf16x8, vb), acc[dt], 0, 0, 0);
            }
        }
        __builtin_amdgcn_s_setprio(0);

        __syncthreads();   // tile t reads done; buf[(t+1)&1] ready
    }

    // ---- epilogue: PV C layout: col = c32 = d-local,
    // row q_local = (r&3) + 8*(r>>2) + 4*h ----
    float* ob = Og + ((size_t)bh * SQ + qbase + w * 32) * DH + c32;
    #pragma unroll
    for (int dt = 0; dt < 4; ++dt) {
        #pragma unroll
        for (int r = 0; r < 16; ++r) {
            const int qrow = (r & 3) + 8 * (r >> 2) + 4 * h;
            ob[(size_t)qrow * DH + dt * 32] = acc[dt][r];
        }
    }
}

extern "C" void kernel_launch(void* const* d_in, const int* in_sizes, int n_in,
                              void* d_out, int out_size, void* d_ws, size_t ws_size,
                              hipStream_t stream) {
    const float* q = (const float*)d_in[0];
    const float* k = (const float*)d_in[1];
    const float* v = (const float*)d_in[2];
    float* o = (float*)d_out;
    dim3 grid((SQ / QB) * 32);   // 1024 WGs
    fa_fwd_buggy<<<grid, 256, 0, stream>>>(q, k, v, o);
}

// Round 15
// 290.736 us; speedup vs baseline: 13.9330x; 1.1931x over previous
//
#include <hip/hip_runtime.h>
#include <hip/hip_bf16.h>
#include <math.h>

// Buggy flash-attn fwd (no acc rescale, running-l division) per 64-wide KV
// block. B=2 H=16 S=4096 D=128, fp32 in/out, bf16 MFMA compute.
// Round 15: exact round-8 structure (best: 299us) + scheduling polish only:
//  - tile loop hand-unrolled x2 -> literal LDS buffer indices, wider sched
//    window (rule #20: no runtime-varying buffer selects)
//  - STORE/LOAD staging moved between ns=0 and ns=1 QK blocks so staging
//    cvt-VALU + DS writes issue under the MFMA shadow (different buffer ->
//    no hazard; barrier unchanged)
// Levers bracketed and rejected: T15 (r9 neutral), 2WG/64KB (r10 spill),
// 3 w/SIMD (r12 spill), BN=32 (r13 scratch), cross-WG 4-wave (r14 negative).

typedef __attribute__((ext_vector_type(8)))  unsigned short ushort8;
typedef __attribute__((ext_vector_type(8)))  __bf16        bf16x8;
typedef __attribute__((ext_vector_type(16))) float         f32x16;
typedef __attribute__((ext_vector_type(4)))  float         floatv4;
typedef __attribute__((ext_vector_type(2)))  unsigned int  uint2v;
typedef __attribute__((ext_vector_type(4)))  unsigned int  uint4v;

#define SQ   4096
#define SKV  4096
#define DH   128
#define BN   64
#define QB   256
#define NT   (SKV / BN)   // 64
#define KLD  136   // K LDS row stride (bf16 elems): 128 + 8 pad
#define VTLD 72    // Vt row stride: 64 data + 8 pad, 8-unit XOR swizzled
#define KBUF (64 * KLD)
#define VBUF (DH * VTLD)

static __device__ __forceinline__ unsigned pk2(float lo, float hi) {
    unsigned r;
    asm("v_cvt_pk_bf16_f32 %0, %1, %2" : "=v"(r) : "v"(lo), "v"(hi));
    return r;
}

__global__ __launch_bounds__(512, 2) void fa_fwd_buggy(
    const float* __restrict__ Qg, const float* __restrict__ Kg,
    const float* __restrict__ Vg, float* __restrict__ Og)
{
    // LDS: 2 x (K 17.4KB + Vt 18.4KB) = 70KB; 1 WG/CU (reg-capped at 2 w/SIMD).
    __shared__ unsigned short K_lds[2 * KBUF];
    __shared__ unsigned short Vt_lds[2 * VBUF];

    const int tid  = threadIdx.x;
    const int w    = tid >> 6;      // wave 0..7, owns q rows w*32..w*32+31
    const int lane = tid & 63;
    const int c32  = lane & 31;
    const int h    = lane >> 5;     // k-half within fragments

    // bh->XCD grouping: all 16 qtiles of one bh on one XCD.
    const int wgid  = blockIdx.x;            // 0..511
    const int bh    = (wgid & 7) * 4 + (wgid >> 7);
    const int qtile = (wgid >> 3) & 15;
    const int qbase = qtile * QB;
    const float qscale = 0.08838834764831845f * 1.44269504088896341f;

    // ---- Q fragments (B-operand of swapped QK): col n = c32 = q-row,
    // k = ds*16 + h*8 + j ----
    const float* Qrow = Qg + ((size_t)bh * SQ + qbase + w * 32 + c32) * DH;
    ushort8 qf[8];
    #pragma unroll
    for (int ds = 0; ds < 8; ++ds) {
        floatv4 a = *(const floatv4*)(Qrow + ds * 16 + h * 8);
        floatv4 b = *(const floatv4*)(Qrow + ds * 16 + h * 8 + 4);
        uint4v u;
        u[0] = pk2(a[0]*qscale, a[1]*qscale);
        u[1] = pk2(a[2]*qscale, a[3]*qscale);
        u[2] = pk2(b[0]*qscale, b[1]*qscale);
        u[3] = pk2(b[2]*qscale, b[3]*qscale);
        qf[ds] = __builtin_bit_cast(ushort8, u);
    }

    f32x16 acc[4];
    #pragma unroll
    for (int i = 0; i < 4; ++i)
        #pragma unroll
        for (int r = 0; r < 16; ++r) acc[i][r] = 0.f;

    float l_run = 0.f;   // running denominator, m-hat = 0 domain

    const float* Kbh = Kg + (size_t)bh * SKV * DH;
    const float* Vbh = Vg + (size_t)bh * SKV * DH;

    // staging thread mappings (512 threads) — identical to round 8
    const int n_k = tid >> 3;          // K row 0..63
    const int u_k = tid & 7;           // K 8-elem units {u_k, u_k+8}
    const int dq  = tid & 31;          // V d-block (d = 4*dq)
    const int nq  = tid >> 5;          // V n-block 0..15 (n = 4*nq)
    const int vswz = (dq >> 1) & 7;    // (d>>3)&7

    floatv4 ka0, ka1, kb0, kb1;        // K stage regs
    floatv4 va0, va1, va2, va3;        // V stage regs

#define LOAD_TILE(N0) do {                                                   \
        const float* ks_ = Kbh + (size_t)((N0) + n_k) * DH + u_k * 8;        \
        ka0 = *(const floatv4*)(ks_);        ka1 = *(const floatv4*)(ks_+4); \
        kb0 = *(const floatv4*)(ks_ + 64);   kb1 = *(const floatv4*)(ks_+68);\
        const float* vs_ = Vbh + (size_t)((N0) + nq * 4) * DH + dq * 4;      \
        va0 = *(const floatv4*)(vs_);        va1 = *(const floatv4*)(vs_+DH);\
        va2 = *(const floatv4*)(vs_+2*DH);   va3 = *(const floatv4*)(vs_+3*DH);\
    } while (0)

#define STORE_TILE(B) do {                                                   \
        unsigned short* kd_ = &K_lds[(B) * KBUF];                            \
        unsigned short* vd_ = &Vt_lds[(B) * VBUF];                           \
        uint4v u_;                                                           \
        u_[0]=pk2(ka0[0],ka0[1]); u_[1]=pk2(ka0[2],ka0[3]);                  \
        u_[2]=pk2(ka1[0],ka1[1]); u_[3]=pk2(ka1[2],ka1[3]);                  \
        *(uint4v*)&kd_[n_k * KLD + u_k * 8] = u_;                            \
        u_[0]=pk2(kb0[0],kb0[1]); u_[1]=pk2(kb0[2],kb0[3]);                  \
        u_[2]=pk2(kb1[0],kb1[1]); u_[3]=pk2(kb1[2],kb1[3]);                  \
        *(uint4v*)&kd_[n_k * KLD + (u_k + 8) * 8] = u_;                      \
        _Pragma("unroll")                                                    \
        for (int i_ = 0; i_ < 4; ++i_) {                                     \
            const int d_ = dq * 4 + i_;                                      \
            uint2v p_;                                                       \
            p_[0] = pk2(va0[i_], va1[i_]);                                   \
            p_[1] = pk2(va2[i_], va3[i_]);                                   \
            const int unit_ = (nq >> 1) ^ vswz;                              \
            *(uint2v*)&vd_[d_ * VTLD + unit_ * 8 + (nq & 1) * 4] = p_;       \
        }                                                                    \
    } while (0)

// One QK 32x32 block (8 MFMA) from K buffer BUF, rows ns*32..+31 -> S
#define QK_NS(S, BUF, NS) do {                                               \
        const unsigned short* kb_ = &K_lds[(BUF) * KBUF];                    \
        _Pragma("unroll")                                                    \
        for (int r_ = 0; r_ < 16; ++r_) S[r_] = 0.f;                         \
        __builtin_amdgcn_s_setprio(1);                                       \
        _Pragma("unroll")                                                    \
        for (int ds_ = 0; ds_ < 8; ++ds_) {                                  \
            ushort8 kf_ = *(const ushort8*)&kb_[((NS) * 32 + c32) * KLD      \
                                                + ds_ * 16 + h * 8];         \
            S = __builtin_amdgcn_mfma_f32_32x32x16_bf16(                     \
                    __builtin_bit_cast(bf16x8, kf_),                         \
                    __builtin_bit_cast(bf16x8, qf[ds_]), S, 0, 0, 0);        \
        }                                                                    \
        __builtin_amdgcn_s_setprio(0);                                       \
    } while (0)

// Full tile body for tile index T using literal buffer BUF (= T&1).
// Staging for T+1 is issued BETWEEN the two QK blocks (MFMA shadow).
#define TILE_BODY(T, BUF) do {                                               \
        f32x16 s0, s1;                                                       \
        QK_NS(s0, BUF, 0);                                                   \
        if ((T) + 1 < NT) {                                                  \
            STORE_TILE(1 - (BUF));                                           \
            if ((T) + 2 < NT) LOAD_TILE((size_t)((T) + 2) * BN);             \
        }                                                                    \
        QK_NS(s1, BUF, 1);                                                   \
        /* softmax, buggy variant, m-hat = 0 */                              \
        _Pragma("unroll")                                                    \
        for (int r_ = 0; r_ < 16; ++r_) s0[r_] = __builtin_amdgcn_exp2f(s0[r_]); \
        _Pragma("unroll")                                                    \
        for (int r_ = 0; r_ < 16; ++r_) s1[r_] = __builtin_amdgcn_exp2f(s1[r_]); \
        float q0_ = (s0[0]+s0[1])+(s0[2]+s0[3]);                             \
        float q1_ = (s0[4]+s0[5])+(s0[6]+s0[7]);                             \
        float q2_ = (s0[8]+s0[9])+(s0[10]+s0[11]);                           \
        float q3_ = (s0[12]+s0[13])+(s0[14]+s0[15]);                         \
        float q4_ = (s1[0]+s1[1])+(s1[2]+s1[3]);                             \
        float q5_ = (s1[4]+s1[5])+(s1[6]+s1[7]);                             \
        float q6_ = (s1[8]+s1[9])+(s1[10]+s1[11]);                           \
        float q7_ = (s1[12]+s1[13])+(s1[14]+s1[15]);                         \
        float ps_ = ((q0_+q1_)+(q2_+q3_)) + ((q4_+q5_)+(q6_+q7_));           \
        ps_ += __shfl_xor(ps_, 32);                                          \
        const float ln_ = l_run + ps_;                                       \
        l_run = ln_;                                                         \
        const float inv_ = __builtin_amdgcn_rcpf(ln_);                       \
        unsigned wrd_[2][8];                                                 \
        _Pragma("unroll")                                                    \
        for (int i_ = 0; i_ < 8; ++i_)                                       \
            wrd_[0][i_] = pk2(s0[2*i_] * inv_, s0[2*i_+1] * inv_);           \
        _Pragma("unroll")                                                    \
        for (int i_ = 0; i_ < 8; ++i_)                                       \
            wrd_[1][i_] = pk2(s1[2*i_] * inv_, s1[2*i_+1] * inv_);           \
        ushort8 pa_[4];                                                      \
        _Pragma("unroll")                                                    \
        for (int st_ = 0; st_ < 4; ++st_) {                                  \
            const int ns_   = st_ >> 1;                                      \
            const int base_ = 4 * (st_ & 1);                                 \
            auto rA_ = __builtin_amdgcn_permlane32_swap(                     \
                (int)wrd_[ns_][base_ + 0], (int)wrd_[ns_][base_ + 2], false, false); \
            auto rB_ = __builtin_amdgcn_permlane32_swap(                     \
                (int)wrd_[ns_][base_ + 1], (int)wrd_[ns_][base_ + 3], false, false); \
            uint4v pw_;                                                      \
            pw_[0] = (unsigned)rA_[0];                                       \
            pw_[1] = (unsigned)rB_[0];                                       \
            pw_[2] = (unsigned)rA_[1];                                       \
            pw_[3] = (unsigned)rB_[1];                                       \
            pa_[st_] = __builtin_bit_cast(ushort8, pw_);                     \
        }                                                                    \
        const unsigned short* vb_ = &Vt_lds[(BUF) * VBUF];                   \
        __builtin_amdgcn_s_setprio(1);                                       \
        _Pragma("unroll")                                                    \
        for (int dt_ = 0; dt_ < 4; ++dt_) {                                  \
            const int d_  = dt_ * 32 + c32;                                  \
            const int fz_ = (d_ >> 3) & 7;                                   \
            _Pragma("unroll")                                                \
            for (int st_ = 0; st_ < 4; ++st_) {                              \
                ushort8 vv_ = *(const ushort8*)&vb_[d_ * VTLD                \
                                  + (((2*st_ + h) ^ fz_) * 8)];              \
                acc[dt_] = __builtin_amdgcn_mfma_f32_32x32x16_bf16(          \
                    __builtin_bit_cast(bf16x8, pa_[st_]),                    \
                    __builtin_bit_cast(bf16x8, vv_), acc[dt_], 0, 0, 0);     \
            }                                                                \
        }                                                                    \
        __builtin_amdgcn_s_setprio(0);                                       \
        __syncthreads();                                                     \
    } while (0)

    // prologue: tile 0 -> buf0, tile 1 -> regs
    LOAD_TILE(0);
    STORE_TILE(0);
    LOAD_TILE(BN);
    __syncthreads();

    // main loop, hand-unrolled x2: literal buffer indices (NT = 64, even)
    for (int t = 0; t < NT; t += 2) {
        TILE_BODY(t,     0);
        TILE_BODY(t + 1, 1);
    }

    // ---- epilogue: PV C layout: col = c32 = d-local,
    // row q_local = (r&3) + 8*(r>>2) + 4*h ----
    float* ob = Og + ((size_t)bh * SQ + qbase + w * 32) * DH + c32;
    #pragma unroll
    for (int dt = 0; dt < 4; ++dt) {
        #pragma unroll
        for (int r = 0; r < 16; ++r) {
            const int qrow = (r & 3) + 8 * (r >> 2) + 4 * h;
            ob[(size_t)qrow * DH + dt * 32] = acc[dt][r];
        }
    }
}

extern "C" void kernel_launch(void* const* d_in, const int* in_sizes, int n_in,
                              void* d_out, int out_size, void* d_ws, size_t ws_size,
                              hipStream_t stream) {
    const float* q = (const float*)d_in[0];
    const float* k = (const float*)d_in[1];
    const float* v = (const float*)d_in[2];
    float* o = (float*)d_out;
    dim3 grid((SQ / QB) * 32);   // 512 WGs
    fa_fwd_buggy<<<grid, 512, 0, stream>>>(q, k, v, o);
}